// Round 1
// 677.270 us; speedup vs baseline: 1.1811x; 1.1811x over previous
//
#include <hip/hip_runtime.h>
#include <cmath>

#define BB 16
#define NN 4096
#define DD 1024
#define HH 512
#define OO 4096
#define KSEL 200
#define NCAND 256
#define NT (BB * NN)          // 65536
#define NSLOT (BB * NCAND)    // 4096

typedef __bf16 bf16x8 __attribute__((ext_vector_type(8)));
typedef float floatx4 __attribute__((ext_vector_type(4)));

__device__ __forceinline__ unsigned short f2b(float f) {
    union { float f; unsigned u; } v; v.f = f;
    unsigned r = v.u + 0x7fffu + ((v.u >> 16) & 1u);   // RNE
    return (unsigned short)(r >> 16);
}
__device__ __forceinline__ unsigned pk2(float lo, float hi) {
    return (unsigned)f2b(lo) | ((unsigned)f2b(hi) << 16);
}

// Fast tanh-form GELU for the APPROX scoring pass only.
// gelu_tanh(u) = u * sigmoid(2c(u + 0.044715u^3)), c = sqrt(2/pi).
// |error vs exact erf-GELU| ~1e-3 absolute — far below the bf16 noise already
// present in this pass and well inside the 256-vs-200 candidate margin.
// Exact erff stays in rescore_kernel (final ranking).
__device__ __forceinline__ float fast_gelu(float u) {
    // z = 2c*u + 2c*0.044715*u^3 = u * (1.5957691216 + 0.0713548163*u^2)
    float z = u * fmaf(0.0713548162726f, u * u, 1.5957691216f);
    float e = __expf(z);                       // v_exp_f32 path
    float r = __builtin_amdgcn_rcpf(e + 1.0f); // approx rcp, 1 op
    return u - u * r;                          // u * e/(1+e)
}

// async global->LDS, 16 B per lane.  LDS dest = wave-uniform base + lane*16.
__device__ __forceinline__ void gl16(const void* g, void* l) {
    __builtin_amdgcn_global_load_lds(
        (const __attribute__((address_space(1))) unsigned int*)g,
        (__attribute__((address_space(3))) unsigned int*)l, 16, 0, 0);
}

// ---------------------------------------------------------------------------
// fp32 -> bf16 converter (x, W1, Wp), 8 elems/thread
// ---------------------------------------------------------------------------
__global__ __launch_bounds__(256) void convert_bf16(
    const float* __restrict__ src, unsigned short* __restrict__ dst, int n8)
{
    int i = blockIdx.x * 256 + threadIdx.x;
    if (i >= n8) return;
    float4 a = ((const float4*)src)[2 * i];
    float4 b = ((const float4*)src)[2 * i + 1];
    uint4 o = make_uint4(pk2(a.x, a.y), pk2(a.z, a.w), pk2(b.x, b.y), pk2(b.z, b.w));
    ((uint4*)dst)[i] = o;
}

// ---------------------------------------------------------------------------
// Approx scores, m97-style: A = xb[128 tok], B = W1b[128 h], BK=64,
// global_load_lds staging with XOR-swizzled layout.
// 1D grid of 2048 blocks, XCD-swizzled: each XCD gets a contiguous run of
// 64 token-tiles with all 4 h-tiles ADJACENT -> A-tile re-reads become
// L2-hits (was: 4 fetches across 4 different XCD L2s), W1b (1MB) L2-resident.
// ---------------------------------------------------------------------------
#define BK 64
#define NSCORE_BLK ((HH / 128) * (NT / 128))   // 2048, divisible by 8

__global__ __launch_bounds__(256) void score_mfma(
    const unsigned short* __restrict__ xb, const unsigned short* __restrict__ W1b,
    const float* __restrict__ b1, const float* __restrict__ W2,
    float* __restrict__ partials)
{
    __shared__ __align__(16) unsigned short As[128 * BK];
    __shared__ __align__(16) unsigned short Bs[128 * BK];
    __shared__ float red[2][128];

    const int tid = threadIdx.x;
    // bijective XCD swizzle: hardware round-robins blockIdx%8 across XCDs;
    // give XCD k logical ids [k*256, (k+1)*256) = token-tiles [k*64,(k+1)*64),
    // h-tile fastest within.
    const int bid = blockIdx.x;
    const int swz = (bid & 7) * (NSCORE_BLK / 8) + (bid >> 3);
    const int ht = swz & 3;
    const int h0 = ht * 128;
    const int t0 = (swz >> 2) * 128;

    const int lane = tid & 63;
    const int w = tid >> 6;
    const int wr = w & 1, wc = w >> 1;
    const int l15 = lane & 15, q = lane >> 4;

    // staging geometry: transfer t = i*256 + tid; row = t/8, blk = t%8
    const int srow = tid >> 3;                 // 0..31 (+ i*32)
    const int cb = (tid & 7) ^ (srow & 7);     // swizzled global col-block
    const unsigned short* pA[4];
    const unsigned short* pB[4];
#pragma unroll
    for (int i = 0; i < 4; ++i) {
        pA[i] = xb  + (size_t)(t0 + i * 32 + srow) * DD + cb * 8;
        pB[i] = W1b + (size_t)(h0 + i * 32 + srow) * DD + cb * 8;
    }

    floatx4 acc[4][4];
#pragma unroll
    for (int mi = 0; mi < 4; ++mi)
#pragma unroll
        for (int ni = 0; ni < 4; ++ni) acc[mi][ni] = (floatx4){0.f, 0.f, 0.f, 0.f};

    for (int kc = 0; kc < DD; kc += BK) {
        __syncthreads();   // previous tile fully consumed
#pragma unroll
        for (int i = 0; i < 4; ++i) {
            gl16(pA[i] + kc, &As[(i * 256 + w * 64) * 8]);
            gl16(pB[i] + kc, &Bs[(i * 256 + w * 64) * 8]);
        }
        __syncthreads();   // DMA drained (vmcnt(0) before barrier)
#pragma unroll
        for (int kk = 0; kk < BK; kk += 32) {
            const int kb = kk >> 3;
            bf16x8 af[4], bf[4];
#pragma unroll
            for (int mi = 0; mi < 4; ++mi) {
                const int r = wr * 64 + mi * 16 + l15;
                af[mi] = *(const bf16x8*)&As[r * BK + (((kb + q) ^ (r & 7)) << 3)];
            }
#pragma unroll
            for (int ni = 0; ni < 4; ++ni) {
                const int r = wc * 64 + ni * 16 + l15;
                bf[ni] = *(const bf16x8*)&Bs[r * BK + (((kb + q) ^ (r & 7)) << 3)];
            }
#pragma unroll
            for (int mi = 0; mi < 4; ++mi)
#pragma unroll
                for (int ni = 0; ni < 4; ++ni)
                    acc[mi][ni] = __builtin_amdgcn_mfma_f32_16x16x32_bf16(af[mi], bf[ni], acc[mi][ni], 0, 0, 0);
        }
    }

    // epilogue: fast gelu + W2-dot over 128 h, reduce cols -> tokens
    float s[4][4];
#pragma unroll
    for (int mi = 0; mi < 4; ++mi)
#pragma unroll
        for (int r = 0; r < 4; ++r) s[mi][r] = 0.f;
#pragma unroll
    for (int ni = 0; ni < 4; ++ni) {
        const int n = h0 + wc * 64 + ni * 16 + l15;
        const float bias = b1[n];
        const float w2v = W2[n];
#pragma unroll
        for (int mi = 0; mi < 4; ++mi)
#pragma unroll
            for (int r = 0; r < 4; ++r) {
                float u = acc[mi][ni][r] + bias;
                s[mi][r] = fmaf(fast_gelu(u), w2v, s[mi][r]);
            }
    }
#pragma unroll
    for (int mi = 0; mi < 4; ++mi)
#pragma unroll
        for (int r = 0; r < 4; ++r) {
#pragma unroll
            for (int off = 1; off < 16; off <<= 1)
                s[mi][r] += __shfl_xor(s[mi][r], off, 64);
        }
    __syncthreads();
    if (l15 == 0) {
#pragma unroll
        for (int mi = 0; mi < 4; ++mi)
#pragma unroll
            for (int r = 0; r < 4; ++r)
                red[wc][wr * 64 + mi * 16 + q * 4 + r] = s[mi][r];
    }
    __syncthreads();
    if (tid < 128)
        partials[(size_t)ht * NT + t0 + tid] = red[0][tid] + red[1][tid];
}

// ---------------------------------------------------------------------------
// Per-batch candidate select: radix-select 256th-largest approx score,
// compact all > T + equal-T.  Deterministic SET (order immaterial).
// ---------------------------------------------------------------------------
__global__ __launch_bounds__(256) void cand_select(
    const float* __restrict__ partials, int* __restrict__ cand)
{
    __shared__ unsigned uk[NN];
    __shared__ int hist[256];
    __shared__ int eq[64];
    __shared__ int sh_pref, sh_rk, sh_cntgt, sh_eqcnt;
    const int b = blockIdx.x, tid = threadIdx.x;

    for (int i = tid; i < NN; i += 256) {
        const int t = b * NN + i;
        float v = partials[t] + partials[NT + t] + partials[2 * NT + t] + partials[3 * NT + t];
        union { float f; unsigned u; } c; c.f = v;
        uk[i] = (c.u & 0x80000000u) ? ~c.u : (c.u | 0x80000000u);
    }
    if (tid == 0) { sh_pref = 0; sh_rk = NCAND; }
    __syncthreads();

    for (int sh = 24; sh >= 0; sh -= 8) {
        hist[tid] = 0;
        __syncthreads();
        const unsigned pref = (unsigned)sh_pref;
        for (int i = tid; i < NN; i += 256) {
            unsigned k = uk[i];
            bool match = (sh == 24) || (((k ^ pref) >> (sh + 8)) == 0);
            if (match) atomicAdd(&hist[(k >> sh) & 255], 1);
        }
        __syncthreads();
        if (tid == 0) {
            int rk = sh_rk, cum = 0;
            for (int bin = 255; bin >= 0; --bin) {
                int c = hist[bin];
                if (cum + c >= rk) { sh_pref = (int)(pref | ((unsigned)bin << sh)); sh_rk = rk - cum; break; }
                cum += c;
            }
        }
        __syncthreads();
    }
    const unsigned T = (unsigned)sh_pref;
    if (tid == 0) { sh_cntgt = 0; sh_eqcnt = 0; }
    cand[b * NCAND + tid] = 0;
    __syncthreads();
    for (int i = tid; i < NN; i += 256) {
        unsigned k = uk[i];
        if (k > T) {
            int p = atomicAdd(&sh_cntgt, 1);
            if (p < NCAND) cand[b * NCAND + p] = i;
        } else if (k == T) {
            int p = atomicAdd(&sh_eqcnt, 1);
            if (p < 64) eq[p] = i;
        }
    }
    __syncthreads();
    if (tid == 0) {
        int cg = sh_cntgt; if (cg > NCAND) cg = NCAND;
        int ec = sh_eqcnt; if (ec > 64) ec = 64;
        int need = NCAND - cg; if (need > ec) need = ec; if (need < 0) need = 0;
        for (int a = 1; a < ec; ++a) {
            int v = eq[a]; int j = a - 1;
            while (j >= 0 && eq[j] > v) { eq[j + 1] = eq[j]; --j; }
            eq[j + 1] = v;
        }
        for (int j = 0; j < need; ++j) cand[b * NCAND + cg + j] = eq[j];
    }
}

// ---------------------------------------------------------------------------
// Exact fp32 rescore, 64x64 tiles -> grid (64, 8) = 512 blocks.
// pc[8][NSLOT] partials over h-tiles of 64 (gelu needs full K -> h split only).
// NOTE: keeps exact erff — this pass decides the final ranking.
// ---------------------------------------------------------------------------
#define RT 64
#define RLDP 68   // 68*4 bytes, multiple of 16 -> aligned float4 rows

__global__ __launch_bounds__(256) void rescore_kernel(
    const float* __restrict__ x, const int* __restrict__ cand,
    const float* __restrict__ W1, const float* __restrict__ b1,
    const float* __restrict__ W2, float* __restrict__ pc)
{
    __shared__ float As[16][RLDP];
    __shared__ float Bs[16][RLDP];
    __shared__ int rowbase[RT];

    const int tid = threadIdx.x;
    const int s0 = blockIdx.x * RT;
    const int h0 = blockIdx.y * RT;
    const int tx = tid & 15;
    const int ty = tid >> 4;
    const int lr = tid >> 2;
    const int lq = tid & 3;

    if (tid < RT) {
        const int slot = s0 + tid;
        rowbase[tid] = (slot >> 8) * NN + (cand[slot] & (NN - 1));
    }
    __syncthreads();

    const float* Arow = x + (size_t)rowbase[lr] * DD;
    const float* Brow = W1 + (size_t)(h0 + lr) * DD;

    float acc[4][4];
#pragma unroll
    for (int i = 0; i < 4; ++i)
#pragma unroll
        for (int j = 0; j < 4; ++j) acc[i][j] = 0.0f;

    for (int kc = 0; kc < DD; kc += 16) {
        float4 a = *(const float4*)(Arow + kc + lq * 4);
        float4 wv = *(const float4*)(Brow + kc + lq * 4);
        __syncthreads();
        As[lq * 4 + 0][lr] = a.x; As[lq * 4 + 1][lr] = a.y;
        As[lq * 4 + 2][lr] = a.z; As[lq * 4 + 3][lr] = a.w;
        Bs[lq * 4 + 0][lr] = wv.x; Bs[lq * 4 + 1][lr] = wv.y;
        Bs[lq * 4 + 2][lr] = wv.z; Bs[lq * 4 + 3][lr] = wv.w;
        __syncthreads();
#pragma unroll
        for (int kk = 0; kk < 16; ++kk) {
            float ra[4], rb[4];
            *(float4*)&ra[0] = *(const float4*)&As[kk][ty * 4];
            *(float4*)&rb[0] = *(const float4*)&Bs[kk][tx * 4];
#pragma unroll
            for (int i = 0; i < 4; ++i)
#pragma unroll
                for (int j = 0; j < 4; ++j)
                    acc[i][j] = fmaf(ra[i], rb[j], acc[i][j]);
        }
    }

    float s[4];
#pragma unroll
    for (int i = 0; i < 4; ++i) s[i] = 0.0f;
#pragma unroll
    for (int j = 0; j < 4; ++j) {
        const int h = h0 + tx * 4 + j;
        const float bias = b1[h];
        const float w2v = W2[h];
#pragma unroll
        for (int i = 0; i < 4; ++i) {
            float u = acc[i][j] + bias;
            float g = 0.5f * u * (1.0f + erff(u * 0.70710678118654752440f));
            s[i] = fmaf(g, w2v, s[i]);
        }
    }
#pragma unroll
    for (int i = 0; i < 4; ++i) {
#pragma unroll
        for (int off = 8; off > 0; off >>= 1)
            s[i] += __shfl_down(s[i], off, 16);
    }
    if (tx == 0) {
#pragma unroll
        for (int i = 0; i < 4; ++i)
            pc[(size_t)blockIdx.y * NSLOT + s0 + ty * 4 + i] = s[i];
    }
}

// ---------------------------------------------------------------------------
// Final exact top-200: bitonic sort of 256 packed keys per batch.
// key = mono(score)<<12 | (4095 - token)  -> desc sort == score desc, tok asc.
// ---------------------------------------------------------------------------
__global__ __launch_bounds__(256) void final_topk(
    const float* __restrict__ pc, const int* __restrict__ cand,
    int* __restrict__ topk)
{
    __shared__ unsigned long long keys[NCAND];
    const int b = blockIdx.x, tid = threadIdx.x;
    const int slot = b * NCAND + tid;
    float es = 0.f;
#pragma unroll
    for (int g = 0; g < 8; ++g) es += pc[(size_t)g * NSLOT + slot];
    const int tok = cand[slot];
    union { float f; unsigned u; } c; c.f = es;
    unsigned mono = (c.u & 0x80000000u) ? ~c.u : (c.u | 0x80000000u);
    keys[tid] = ((unsigned long long)mono << 12) | (unsigned)(4095 - tok);
    __syncthreads();

    for (int k = 2; k <= NCAND; k <<= 1) {
        for (int j = k >> 1; j > 0; j >>= 1) {
            const int p = tid ^ j;
            const unsigned long long a = keys[tid];
            const unsigned long long o = keys[p];
            const unsigned long long hi = a > o ? a : o;
            const unsigned long long lo = a > o ? o : a;
            const unsigned long long nv = ((tid < p) == ((tid & k) == 0)) ? hi : lo;
            __syncthreads();
            keys[tid] = nv;
            __syncthreads();
        }
    }
    if (tid < KSEL) topk[b * KSEL + tid] = 4095 - (int)(keys[tid] & 4095u);
}

// ---------------------------------------------------------------------------
// Projection, m97-style with gathered A rows (xb) and Wpb, fp32 out + bp.
// 1D grid of 800 blocks, XCD-swizzled (o-tile fastest): the 32 blocks sharing
// one gathered A row-tile run adjacent on one XCD -> scattered-row reads hit L2.
// ---------------------------------------------------------------------------
#define NPROJ_BLK (((BB * KSEL) / 128) * (OO / 128))   // 25*32 = 800, /8 = 100

__global__ __launch_bounds__(256) void proj_mfma(
    const unsigned short* __restrict__ xb, const int* __restrict__ topk,
    const unsigned short* __restrict__ Wpb, const float* __restrict__ bp,
    float* __restrict__ out)
{
    __shared__ __align__(16) unsigned short As[128 * BK];
    __shared__ __align__(16) unsigned short Bs[128 * BK];
    __shared__ int rowbase[128];

    const int tid = threadIdx.x;
    const int bid = blockIdx.x;
    const int swz = (bid & 7) * (NPROJ_BLK / 8) + (bid >> 3);
    const int r0 = (swz >> 5) * 128;     // 25 row-tiles, slow
    const int o0 = (swz & 31) * 128;     // 32 o-tiles, fast (reuse gathered A)
    const int lane = tid & 63;
    const int w = tid >> 6;
    const int wr = w & 1, wc = w >> 1;
    const int l15 = lane & 15, q = lane >> 4;

    if (tid < 128) {
        const int r = r0 + tid;
        rowbase[tid] = (r / KSEL) * NN + (topk[r] & (NN - 1));
    }
    __syncthreads();

    const int srow = tid >> 3;
    const int cb = (tid & 7) ^ (srow & 7);
    const unsigned short* pA[4];
    const unsigned short* pB[4];
#pragma unroll
    for (int i = 0; i < 4; ++i) {
        pA[i] = xb  + (size_t)rowbase[i * 32 + srow] * DD + cb * 8;
        pB[i] = Wpb + (size_t)(o0 + i * 32 + srow) * DD + cb * 8;
    }

    floatx4 acc[4][4];
#pragma unroll
    for (int mi = 0; mi < 4; ++mi)
#pragma unroll
        for (int ni = 0; ni < 4; ++ni) acc[mi][ni] = (floatx4){0.f, 0.f, 0.f, 0.f};

    for (int kc = 0; kc < DD; kc += BK) {
        __syncthreads();
#pragma unroll
        for (int i = 0; i < 4; ++i) {
            gl16(pA[i] + kc, &As[(i * 256 + w * 64) * 8]);
            gl16(pB[i] + kc, &Bs[(i * 256 + w * 64) * 8]);
        }
        __syncthreads();
#pragma unroll
        for (int kk = 0; kk < BK; kk += 32) {
            const int kb = kk >> 3;
            bf16x8 af[4], bf[4];
#pragma unroll
            for (int mi = 0; mi < 4; ++mi) {
                const int r = wr * 64 + mi * 16 + l15;
                af[mi] = *(const bf16x8*)&As[r * BK + (((kb + q) ^ (r & 7)) << 3)];
            }
#pragma unroll
            for (int ni = 0; ni < 4; ++ni) {
                const int r = wc * 64 + ni * 16 + l15;
                bf[ni] = *(const bf16x8*)&Bs[r * BK + (((kb + q) ^ (r & 7)) << 3)];
            }
#pragma unroll
            for (int mi = 0; mi < 4; ++mi)
#pragma unroll
                for (int ni = 0; ni < 4; ++ni)
                    acc[mi][ni] = __builtin_amdgcn_mfma_f32_16x16x32_bf16(af[mi], bf[ni], acc[mi][ni], 0, 0, 0);
        }
    }

    float bpv[4];
#pragma unroll
    for (int ni = 0; ni < 4; ++ni) bpv[ni] = bp[o0 + wc * 64 + ni * 16 + l15];
#pragma unroll
    for (int mi = 0; mi < 4; ++mi)
#pragma unroll
        for (int r = 0; r < 4; ++r) {
            const size_t row = (size_t)(r0 + wr * 64 + mi * 16 + q * 4 + r) * OO;
#pragma unroll
            for (int ni = 0; ni < 4; ++ni)
                out[row + o0 + wc * 64 + ni * 16 + l15] = acc[mi][ni][r] + bpv[ni];
        }
}

// ---------------------------------------------------------------------------
extern "C" void kernel_launch(void* const* d_in, const int* in_sizes, int n_in,
                              void* d_out, int out_size, void* d_ws, size_t ws_size,
                              hipStream_t stream) {
    const float* x  = (const float*)d_in[0];
    const float* W1 = (const float*)d_in[1];
    const float* b1 = (const float*)d_in[2];
    const float* W2 = (const float*)d_in[3];
    // d_in[4] = b2: uniform shift -> irrelevant for top-k, scores not output
    const float* Wp = (const float*)d_in[5];
    const float* bp = (const float*)d_in[6];
    float* out = (float*)d_out;

    char* ws = (char*)d_ws;
    unsigned short* xb  = (unsigned short*)(ws);                   // 128 MB
    unsigned short* W1b = (unsigned short*)(ws + 134217728);       // 1 MB
    unsigned short* Wpb = (unsigned short*)(ws + 135266304);       // 8 MB
    float* partials     = (float*)(ws + 143654912);                // 1 MB
    float* pc           = (float*)(ws + 144703488);                // 128 KB
    int*   cand         = (int*)  (ws + 144834560);                // 16 KB
    int*   topk         = (int*)  (ws + 144850944);                // 12.8 KB
    // total ~144.9 MB

    convert_bf16<<<dim3((NT * DD / 8) / 256), 256, 0, stream>>>(x, xb, NT * DD / 8);
    convert_bf16<<<dim3((HH * DD / 8) / 256), 256, 0, stream>>>(W1, W1b, HH * DD / 8);
    convert_bf16<<<dim3((OO * DD / 8) / 256), 256, 0, stream>>>(Wp, Wpb, OO * DD / 8);

    score_mfma<<<dim3(NSCORE_BLK), 256, 0, stream>>>(xb, W1b, b1, W2, partials);

    cand_select<<<dim3(BB), 256, 0, stream>>>(partials, cand);

    rescore_kernel<<<dim3(NSLOT / RT, HH / RT), 256, 0, stream>>>(x, cand, W1, b1, W2, pc);

    final_topk<<<dim3(BB), 256, 0, stream>>>(pc, cand, topk);

    proj_mfma<<<dim3(NPROJ_BLK), 256, 0, stream>>>(xb, topk, Wpb, bp, out);
}